// Round 2
// 261.858 us; speedup vs baseline: 1.0248x; 1.0248x over previous
//
#include <hip/hip_runtime.h>

// Winograd F(4x4,3x3), fp32. x:[16,64,130,130] w:[64,64,3,3] -> y:[16,64,128,128]
// 4-kernel pipeline: filter transform -> input transform (V) -> per-ab GEMM (M) -> output transform.
// Chunked at 8 images so V+M (151 MB) + x/y slices stay Infinity-Cache-resident:
// ws layout: U[36][64][64] | V[36][64][Pchunk] | M[36][64][Pchunk]

__constant__ float c_AT[24] = {   // c_AT[i*4+u] = A_T[u][i] (columns of A_T)
  1.f, 0.f, 0.f, 0.f,
  1.f, 1.f, 1.f, 1.f,
  1.f,-1.f, 1.f,-1.f,
  1.f, 2.f, 4.f, 8.f,
  1.f,-2.f, 4.f,-8.f,
  0.f, 0.f, 0.f, 1.f
};

__device__ __forceinline__ void gl2lds16(const float* g, float* l) {
  // async global->LDS, 16B per lane; LDS dest = wave-uniform base + lane*16
  __builtin_amdgcn_global_load_lds((const __attribute__((address_space(1))) void*)g,
                                   (__attribute__((address_space(3))) void*)l, 16, 0, 0);
}

// ---------------- K0: filter transform U = G w G^T, layout [ab][c][k] ----------------
__global__ __launch_bounds__(256) void k_filter(const float* __restrict__ w,
                                                float* __restrict__ U) {
  int g = blockIdx.x * 256 + threadIdx.x;     // 0..4095
  int k = g & 63;
  int c = g >> 6;
  const float* wp = w + (size_t)(k * 64 + c) * 9;
  float w00 = wp[0], w01 = wp[1], w02 = wp[2];
  float w10 = wp[3], w11 = wp[4], w12 = wp[5];
  float w20 = wp[6], w21 = wp[7], w22 = wp[8];
  const float G[6][3] = {
    {0.25f, 0.f, 0.f},
    {-1.f/6.f, -1.f/6.f, -1.f/6.f},
    {-1.f/6.f,  1.f/6.f, -1.f/6.f},
    {1.f/24.f,  1.f/12.f, 1.f/6.f},
    {1.f/24.f, -1.f/12.f, 1.f/6.f},
    {0.f, 0.f, 1.f}
  };
  float t[6][3];
#pragma unroll
  for (int a = 0; a < 6; ++a) {
    t[a][0] = G[a][0]*w00 + G[a][1]*w10 + G[a][2]*w20;
    t[a][1] = G[a][0]*w01 + G[a][1]*w11 + G[a][2]*w21;
    t[a][2] = G[a][0]*w02 + G[a][1]*w12 + G[a][2]*w22;
  }
#pragma unroll
  for (int a = 0; a < 6; ++a) {
#pragma unroll
    for (int b = 0; b < 6; ++b) {
      float u = G[b][0]*t[a][0] + G[b][1]*t[a][1] + G[b][2]*t[a][2];
      U[(size_t)(a*6+b)*4096 + c*64 + k] = u;
    }
  }
}

// ---------------- K1: input transform V = B^T d B, layout [ab][c][p] ----------------
__global__ __launch_bounds__(256) void k_input(const float* __restrict__ x,
                                               float* __restrict__ V,
                                               int n0, int Pchunk) {
  __shared__ float Ls[34*134];                // 34 rows x 130 cols, row stride 134 (even, non-pow2)
  const int tid  = threadIdx.x;
  const int bi   = blockIdx.x;
  const int band = bi & 3;
  const int c    = (bi >> 2) & 63;
  const int nl   = bi >> 8;
  const float* xp = x + (size_t)((n0 + nl) * 64 + c) * (130*130) + band * 32 * 130;
  for (int idx = tid; idx < 34*65; idx += 256) {       // float2-vectorized load
    int r  = idx / 65;                                 // const-div -> magic mul
    int c2 = idx - r * 65;
    *(float2*)&Ls[r*134 + c2*2] = *(const float2*)(xp + r*130 + c2*2);
  }
  __syncthreads();
  const int tyl = tid >> 5;
  const int tx  = tid & 31;
  const int ty  = band * 8 + tyl;
  const int p   = (nl * 32 + ty) * 32 + tx;
  const float* bl = &Ls[(tyl*4)*134 + tx*4];
  float t1[6][6];
#pragma unroll
  for (int j = 0; j < 6; ++j) {               // columns: t1 = B^T d
    float d0 = bl[0*134+j], d1 = bl[1*134+j], d2 = bl[2*134+j];
    float d3 = bl[3*134+j], d4 = bl[4*134+j], d5 = bl[5*134+j];
    t1[0][j] =  4.f*d0 - 5.f*d2 + d4;
    t1[1][j] = -4.f*d1 - 4.f*d2 + d3 + d4;
    t1[2][j] =  4.f*d1 - 4.f*d2 - d3 + d4;
    t1[3][j] = -2.f*d1 -     d2 + 2.f*d3 + d4;
    t1[4][j] =  2.f*d1 -     d2 - 2.f*d3 + d4;
    t1[5][j] =  4.f*d1 - 5.f*d3 + d5;
  }
  float* vb = V + (size_t)c * Pchunk + p;
  const size_t abs_ = (size_t)64 * Pchunk;
#pragma unroll
  for (int a = 0; a < 6; ++a) {               // rows: V = t1 * B
    float s0=t1[a][0], s1=t1[a][1], s2=t1[a][2], s3=t1[a][3], s4=t1[a][4], s5=t1[a][5];
    float v0 =  4.f*s0 - 5.f*s2 + s4;
    float v1 = -4.f*s1 - 4.f*s2 + s3 + s4;
    float v2 =  4.f*s1 - 4.f*s2 - s3 + s4;
    float v3 = -2.f*s1 -     s2 + 2.f*s3 + s4;
    float v4 =  2.f*s1 -     s2 - 2.f*s3 + s4;
    float v5 =  4.f*s1 - 5.f*s3 + s5;
    vb[(size_t)(a*6+0)*abs_] = v0;
    vb[(size_t)(a*6+1)*abs_] = v1;
    vb[(size_t)(a*6+2)*abs_] = v2;
    vb[(size_t)(a*6+3)*abs_] = v3;
    vb[(size_t)(a*6+4)*abs_] = v4;
    vb[(size_t)(a*6+5)*abs_] = v5;
  }
}

// ---------------- K2: per-ab pure GEMM  M[ab][k][p] = sum_c U[ab][c][k] * V[ab][c][p] ----------------
// block = one (ab, 256-p tile). Double-buffered c-pipeline: 4 chunks of 16 c.
// LDS = 2 x (16x256 V + 16x64 U) = 40 KB -> 4 blocks/CU; stage(next) overlaps compute(cur).
// thread tile 8p x 8k: p in {4pt..4pt+3} u {128+4pt..}, k = 8kt..8kt+7. 64 acc regs.
__global__ __launch_bounds__(256) void k_gemm2(const float* __restrict__ V,
                                               const float* __restrict__ U,
                                               float* __restrict__ M,
                                               int Pchunk, int nPB) {
  __shared__ float Vs[2][16*256];  // 16 KB each half
  __shared__ float Us[2][16*64];   // 4 KB each half
  const int tid  = threadIdx.x;
  const int lane = tid & 63;
  const int wv   = tid >> 6;          // wave id 0..3
  const unsigned bx = blockIdx.x;
  const int ab = bx / (unsigned)nPB;
  const int pb = bx - ab * nPB;
  const int p0 = pb * 256;

  const float* Vab = V + (size_t)ab * 64 * Pchunk + p0;
  const float* Uab = U + (size_t)ab * 4096;

  // stage c-chunk cc (16 rows of V, 16 rows of U) into buffer b
  auto stage = [&](int cc, int b) {
#pragma unroll
    for (int i = 0; i < 4; ++i) {
      int rl = wv * 4 + i;                       // local row 0..15 (wave-uniform)
      gl2lds16(Vab + (size_t)(cc * 16 + rl) * Pchunk + lane * 4, &Vs[b][rl * 256]);
    }
    // U chunk: 1024 contiguous floats; wave wv takes 256-float segment
    gl2lds16(Uab + cc * 1024 + wv * 256 + lane * 4, &Us[b][wv * 256]);
  };

  stage(0, 0);

  const int pt = tid & 31;
  const int kt = tid >> 5;            // 0..7
  float acc[8][8];                    // [ki][pi]
#pragma unroll
  for (int ki = 0; ki < 8; ++ki)
#pragma unroll
    for (int pi = 0; pi < 8; ++pi) acc[ki][pi] = 0.f;

  __syncthreads();                    // drains vmcnt: chunk 0 staged

#pragma unroll
  for (int cc = 0; cc < 4; ++cc) {
    const int b = cc & 1;
    if (cc < 3) stage(cc + 1, b ^ 1); // async prefetch overlaps compute below
#pragma unroll 4
    for (int c = 0; c < 16; ++c) {
      const float4 va = *(const float4*)&Vs[b][c*256 + pt*4];
      const float4 vb = *(const float4*)&Vs[b][c*256 + 128 + pt*4];
      const float4 ua = *(const float4*)&Us[b][c*64 + kt*8];
      const float4 ub = *(const float4*)&Us[b][c*64 + kt*8 + 4];
      const float vv[8] = {va.x, va.y, va.z, va.w, vb.x, vb.y, vb.z, vb.w};
      const float uu[8] = {ua.x, ua.y, ua.z, ua.w, ub.x, ub.y, ub.z, ub.w};
#pragma unroll
      for (int ki = 0; ki < 8; ++ki)
#pragma unroll
        for (int pi = 0; pi < 8; ++pi)
          acc[ki][pi] += uu[ki] * vv[pi];
    }
    __syncthreads();                  // drains prefetch vmcnt + ds reads; safe buffer swap
  }

  // write M[ab][k][p], coalesced float4
#pragma unroll
  for (int ki = 0; ki < 8; ++ki) {
    float* mb = M + ((size_t)ab * 64 + kt*8 + ki) * Pchunk + p0;
    *(float4*)(mb + pt*4)       = make_float4(acc[ki][0], acc[ki][1], acc[ki][2], acc[ki][3]);
    *(float4*)(mb + 128 + pt*4) = make_float4(acc[ki][4], acc[ki][5], acc[ki][6], acc[ki][7]);
  }
}

// ---------------- K3: output transform Y = A_T M A per (k,p) ----------------
__global__ __launch_bounds__(256) void k_out(const float* __restrict__ M,
                                             float* __restrict__ out,
                                             int n0, int Pchunk, int bpk) {
  const unsigned bx = blockIdx.x;
  const int k    = bx / (unsigned)bpk;
  const int pblk = bx - k * bpk;
  const int p    = pblk * 256 + threadIdx.x;
  const int nl = p >> 10;
  const int ty = (p >> 5) & 31;
  const int tx = p & 31;

  const float* mp = M + (size_t)k * Pchunk + p;
  const size_t abstride = (size_t)64 * Pchunk;
  float m[36];
#pragma unroll
  for (int ab = 0; ab < 36; ++ab) m[ab] = mp[(size_t)ab * abstride];

  float Y[4][4];
#pragma unroll
  for (int u = 0; u < 4; ++u)
#pragma unroll
    for (int v = 0; v < 4; ++v) Y[u][v] = 0.f;

#pragma unroll
  for (int i = 0; i < 6; ++i) {
    float R[4] = {0.f, 0.f, 0.f, 0.f};
#pragma unroll
    for (int j = 0; j < 6; ++j) {
      float mm = m[i*6 + j];
#pragma unroll
      for (int v = 0; v < 4; ++v) R[v] += c_AT[j*4 + v] * mm;
    }
#pragma unroll
    for (int u = 0; u < 4; ++u) {
      float au = c_AT[i*4 + u];
#pragma unroll
      for (int v = 0; v < 4; ++v) Y[u][v] += au * R[v];
    }
  }

  float* ob = out + ((size_t)((n0 + nl) * 64 + k) * 128 + ty*4) * 128 + tx*4;
#pragma unroll
  for (int u = 0; u < 4; ++u)
    *(float4*)(ob + (size_t)u * 128) = make_float4(Y[u][0], Y[u][1], Y[u][2], Y[u][3]);
}

extern "C" void kernel_launch(void* const* d_in, const int* in_sizes, int n_in,
                              void* d_out, int out_size, void* d_ws, size_t ws_size,
                              hipStream_t stream) {
  const float* x = (const float*)d_in[0];
  const float* w = (const float*)d_in[1];
  float* out = (float*)d_out;
  float* U = (float*)d_ws;
  const size_t U_bytes = 36ull * 64 * 64 * 4;        // 589824
  const size_t per_n = 2ull * 36 * 1024 * 64 * 4;    // V + M per image = 18874368 B
  size_t avail = ws_size > U_bytes ? ws_size - U_bytes : 0;
  // chunk capped at 8 so V+M (151 MB) + x/y slices stay Infinity-Cache resident
  int chunk = 8;
  while (chunk > 1 && per_n * (size_t)chunk > avail) chunk >>= 1;
  if (per_n > avail) return;                         // ws too small

  k_filter<<<16, 256, 0, stream>>>(w, U);
  for (int n0 = 0; n0 < 16; n0 += chunk) {
    int cn = (16 - n0) < chunk ? (16 - n0) : chunk;
    int Pchunk = cn * 1024;
    float* V = (float*)((char*)d_ws + U_bytes);
    float* M = V + (size_t)36 * 64 * Pchunk;
    int nPB = cn * 4;                                // 256-p tiles per ab
    k_input<<<cn*256,  256, 0, stream>>>(x, V, n0, Pchunk);
    k_gemm2<<<36*nPB,  256, 0, stream>>>(V, U, M, Pchunk, nPB);
    k_out  <<<64*nPB,  256, 0, stream>>>(M, out, n0, Pchunk, nPB);
  }
}